// Round 9
// baseline (320.049 us; speedup 1.0000x reference)
//
#include <hip/hip_runtime.h>
#include <hip/hip_bf16.h>
#include <stdint.h>

#define B_   64
#define N_   128
#define H_   256
#define FH   1024   // 4*H
#define NT   32     // trunks
#define TL   32     // trunk len
#define LV   3
#define OUT_ 10
#define NTRK 96     // level x trunk instances
#define UNITS 384   // NTRK x 4 batch-quarters (M=16 each)

typedef __attribute__((ext_vector_type(4))) int   int4v;
typedef __attribute__((ext_vector_type(4))) float f32x4;

#define QW  (0.0625f / 127.0f)         // weight quant scale
#define QH  (1.0f / 127.0f)            // h quant scale
#define QS  (QW * QH)                  // combined dequant for i32 acc
#define L2E 1.442695041f               // log2(e)
#define QSI (-L2E * QS)                // sigmoid-gate dequant (pre-negated+scaled)
#define QSG (2.0f * L2E * QS)          // tanh-gate dequant
#define C2  (2.0f * L2E)               // tanh(c) input scale

__device__ inline float exp2f_(float x) { return __builtin_amdgcn_exp2f(x); }
__device__ inline float rcpf_(float x)  { return __builtin_amdgcn_rcpf(x); }

// merged prep. blocks 0..767: u/v. blocks 768..1535: W_hh->int8 + out init.
// block 1536: LPT sort + W_lin transpose (wlT[l][o][k]).
// (R2 lesson: fusing prep into the main kernel cost 2x on the main dispatch;
// the ~72us total-vs-dispatch gap is fixed harness tax.)
__global__ void prep_all(const float* __restrict__ W_enc, const float* __restrict__ b_enc,
                         const float* __restrict__ W_ih, const float* __restrict__ b_ih,
                         const float* __restrict__ b_hh, const float* __restrict__ W_hh,
                         const float* __restrict__ b_lin, const float* __restrict__ W_lin,
                         const int* __restrict__ trunk_len,
                         float* __restrict__ u, float* __restrict__ v,
                         char* __restrict__ whh_i8, float* __restrict__ out,
                         int* __restrict__ sorted, float* __restrict__ wlT) {
    int blk = blockIdx.x;
    int tid = threadIdx.x;
    if (blk < 768) {
        int j = blk * 4 + (tid >> 6);   // 0..3071
        int lane = tid & 63;
        const float4 w  = ((const float4*)(W_ih + (size_t)j * H_))[lane];
        const float4 we = ((const float4*)W_enc)[lane];
        const float4 be = ((const float4*)b_enc)[lane];
        float du = w.x * we.x + w.y * we.y + w.z * we.z + w.w * we.w;
        float dv = w.x * be.x + w.y * be.y + w.z * be.z + w.w * be.w;
        for (int m = 32; m >= 1; m >>= 1) { du += __shfl_xor(du, m); dv += __shfl_xor(dv, m); }
        if (lane == 0) {
            int g = (j & 1023) >> 8;
            float s = (g == 2) ? (2.0f * L2E) : (-L2E);
            u[j] = s * du;
            v[j] = s * (dv + b_ih[j] + b_hh[j]);
        }
    } else if (blk < 1536) {
        int gid = (blk - 768) * 256 + tid;   // 0..196607, each converts 4
        const float4 w = ((const float4*)W_hh)[gid];
        char4 o;
        int a0 = __float2int_rn(w.x * (127.0f / 0.0625f));
        int a1 = __float2int_rn(w.y * (127.0f / 0.0625f));
        int a2 = __float2int_rn(w.z * (127.0f / 0.0625f));
        int a3 = __float2int_rn(w.w * (127.0f / 0.0625f));
        a0 = a0 > 127 ? 127 : (a0 < -127 ? -127 : a0);
        a1 = a1 > 127 ? 127 : (a1 < -127 ? -127 : a1);
        a2 = a2 > 127 ? 127 : (a2 < -127 ? -127 : a2);
        a3 = a3 > 127 ? 127 : (a3 < -127 ? -127 : a3);
        o.x = (char)a0; o.y = (char)a1; o.z = (char)a2; o.w = (char)a3;
        ((char4*)whh_i8)[gid] = o;
        if (gid < B_ * OUT_) {
            int oo = gid % OUT_;
            out[gid] = b_lin[oo] + b_lin[OUT_ + oo] + b_lin[2 * OUT_ + oo];
        }
    } else {
        // LPT order: sorted[rank] = trunk id, rank 0 = longest
        if (tid < NTRK) {
            int li = trunk_len[tid]; if (li < 1) li = 1;
            int rank = 0;
            for (int j2 = 0; j2 < NTRK; ++j2) {
                int lj = trunk_len[j2]; if (lj < 1) lj = 1;
                rank += (lj > li) || (lj == li && j2 < tid);
            }
            sorted[rank] = tid;
        }
        // W_lin transpose: wlT[(l*OUT_+o)*H_ + k] = W_lin[(l*H_+k)*OUT_ + o]
        for (int idx = tid; idx < LV * OUT_ * H_; idx += 256) {
            int l = idx / (OUT_ * H_);
            int rem = idx - l * OUT_ * H_;
            int o = rem >> 8;            // / H_
            int k = rem & 255;           // % H_
            wlT[idx] = W_lin[((size_t)l * H_ + k) * OUT_ + o];
        }
    }
}

// One-unit-per-block LSTM. 384 blocks x 512 threads (8 waves), block b ->
// (rank b>>2, quarter b&3), LPT-ordered so blocks 0..255 (longest 64 trunks
// x4) get one CU each and blocks 256..383 (shortest 32 trunks) co-reside as
// the SECOND block on a CU.
// R8 rationale: step time was invariant across 2 vs 4 phase-locked
// waves/SIMD (R1~R6~R7) — same-block waves hit the ds_read->MFMA->trans->
// ds_write->barrier skeleton in lockstep and cannot hide each other's
// stalls (~40-50% of the 5000-cyc step). The untried lever is co-resident
// INDEPENDENT blocks: at 512 thr / 128 VGPR, 2 blocks/CU = 4 waves/SIMD fit
// exactly in the 128-VGPR occupancy tier. Un-synchronized blocks interleave
// issue during each other's stalls. Pole block shares its CU only for the
// short co-tenant's ~10 steps. Work-queue + claim atomics deleted.
// __launch_bounds__(512,4): hard-cap VGPR at 128 (spill => WRITE_SIZE blows
// up => revert condition; R7 measured exactly 128 so it should just fit).
__global__ __launch_bounds__(512, 4) __attribute__((amdgpu_waves_per_eu(4, 4)))
void lstm_main(const float* __restrict__ bfeat, const int* __restrict__ trunk_idx,
               const int* __restrict__ trunk_len,
               const char* __restrict__ whh_i8,
               const float* __restrict__ u, const float* __restrict__ v,
               const float* __restrict__ wlT, const int* __restrict__ sorted,
               float* __restrict__ out) {
    __shared__ __align__(16) char hbuf[2][16][272];   // int8 h, parity dbuf, 256+16 pad
    __shared__ __align__(16) float strunk[TL][16];    // all step scalars for the unit

    const int tid = threadIdx.x;
    const int w = tid >> 6;              // wave 0..7 -> col tiles 2w, 2w+1 per gate
    const int lane = tid & 63;
    const int col = lane & 15;
    const int q = lane >> 4;

    // loop-invariant zero C for MFMA chain heads
    int4v z4; z4[0] = 0; z4[1] = 0; z4[2] = 0; z4[3] = 0;
    asm volatile("" : "+v"(z4));

    const int uid = blockIdx.x;
    const int tt = sorted[uid >> 2];
    const int l = tt >> 5;
    const int b0 = (uid & 3) * 16;

    int len = trunk_len[tt];
    if (len < 1) len = 1;
    const int* tix = trunk_idx + tt * TL;
    const char* whh_l = whh_i8 + (size_t)l * FH * H_;

    // scalar preload: thread tid -> (step p = tid>>4, row m = tid&15).
    // One global load per thread, overlapped with the Breg/u/v loads.
    if (tid < (len << 4))
        strunk[tid >> 4][tid & 15] = bfeat[(b0 + (tid & 15)) * N_ + tix[tid >> 4]];

    // W_hh fragments: wave w owns gate cols j = g*256 + (2w+t)*16 + col.
    int4v Breg[4][2][4];
    #pragma unroll
    for (int g = 0; g < 4; ++g)
        #pragma unroll
        for (int t = 0; t < 2; ++t) {
            int j = g * 256 + (2 * w + t) * 16 + col;
            const char* bp = whh_l + (size_t)j * H_ + q * 16;
            #pragma unroll
            for (int k = 0; k < 4; ++k)
                Breg[g][t][k] = *(const int4v*)(bp + k * 64);
        }

    float u_r[4][2], v_r[4][2];
    {
        const float* u_l = u + l * FH;
        const float* v_l = v + l * FH;
        #pragma unroll
        for (int g = 0; g < 4; ++g)
            #pragma unroll
            for (int t = 0; t < 2; ++t) {
                int j = g * 256 + (2 * w + t) * 16 + col;
                u_r[g][t] = u_l[j];
                v_r[g][t] = v_l[j];
            }
    }

    // pin Breg: non-rematerializable -> resident or visibly spilled
    #pragma unroll
    for (int g = 0; g < 4; ++g)
        #pragma unroll
        for (int t = 0; t < 2; ++t)
            #pragma unroll
            for (int k = 0; k < 4; ++k)
                asm volatile("" : "+v"(Breg[g][t][k]));

    float c_r[4][2];                 // [rg][tile]

    __syncthreads();                 // strunk ready

    // ---- peeled step 0: c0 = 0 ----
    {
        f32x4 sv = *(const f32x4*)&strunk[0][q * 4];
        #pragma unroll
        for (int t = 0; t < 2; ++t)
            #pragma unroll
            for (int rg = 0; rg < 4; ++rg) {
                float xi = fmaf(sv[rg], u_r[0][t], v_r[0][t]);
                float xg = fmaf(sv[rg], u_r[2][t], v_r[2][t]);
                float xo = fmaf(sv[rg], u_r[3][t], v_r[3][t]);
                float ei = exp2f_(xi);
                float eg = exp2f_(xg);
                float eo = exp2f_(xo);
                float cn = (eg - 1.0f) * rcpf_((1.0f + ei) * (1.0f + eg));
                c_r[rg][t] = cn;
                float ec = exp2f_(C2 * cn);
                float hq = 127.0f * (ec - 1.0f) * rcpf_((1.0f + eo) * (1.0f + ec));
                hbuf[1][q * 4 + rg][(2 * w + t) * 16 + col] = (char)__float2int_rn(hq);
            }
        __syncthreads();
    }

    for (int p = 1; p < len; ++p) {
        const int ri = p & 1, wi = ri ^ 1;

        f32x4 sv = *(const f32x4*)&strunk[p][q * 4];

        // k-outer MFMA: one a_f quad live at a time; 8 independent
        // acc chains (4 gates x 2 tiles) per wave.
        int4v acc[4][2];
        #pragma unroll
        for (int k = 0; k < 4; ++k) {
            int4v af = *(const int4v*)&hbuf[ri][col][k * 64 + q * 16];
            if (k == 0) {
                #pragma unroll
                for (int g = 0; g < 4; ++g)
                    #pragma unroll
                    for (int t = 0; t < 2; ++t)
                        acc[g][t] = __builtin_amdgcn_mfma_i32_16x16x64_i8(af, Breg[g][t][0], z4, 0, 0, 0);
            } else {
                #pragma unroll
                for (int g = 0; g < 4; ++g)
                    #pragma unroll
                    for (int t = 0; t < 2; ++t)
                        acc[g][t] = __builtin_amdgcn_mfma_i32_16x16x64_i8(af, Breg[g][t][k], acc[g][t], 0, 0, 0);
            }
        }

        #pragma unroll
        for (int t = 0; t < 2; ++t)
            #pragma unroll
            for (int rg = 0; rg < 4; ++rg) {
                float xi = fmaf((float)acc[0][t][rg], QSI, fmaf(sv[rg], u_r[0][t], v_r[0][t]));
                float xf = fmaf((float)acc[1][t][rg], QSI, fmaf(sv[rg], u_r[1][t], v_r[1][t]));
                float xg = fmaf((float)acc[2][t][rg], QSG, fmaf(sv[rg], u_r[2][t], v_r[2][t]));
                float xo = fmaf((float)acc[3][t][rg], QSI, fmaf(sv[rg], u_r[3][t], v_r[3][t]));
                float ei = exp2f_(xi);
                float ef = exp2f_(xf);
                float eg = exp2f_(xg);
                float eo = exp2f_(xo);
                float sf = rcpf_(1.0f + ef);                               // sigmoid(f)
                float ig = (eg - 1.0f) * rcpf_((1.0f + ei) * (1.0f + eg)); // sig(i)*tanh(g)
                float cn = fmaf(sf, c_r[rg][t], ig);
                c_r[rg][t] = cn;
                float ec = exp2f_(C2 * cn);
                float hq = 127.0f * (ec - 1.0f) * rcpf_((1.0f + eo) * (1.0f + ec));
                hbuf[wi][q * 4 + rg][(2 * w + t) * 16 + col] = (char)__float2int_rn(hq);
            }

        __syncthreads();   // lgkmcnt+s_barrier only: no vmem in the loop
    }

    // epilogue: h_last in hbuf[len & 1]; bias pre-initialized by prep.
    // 160 threads, ONE atomicAdd per output element (R4 lesson: atomic
    // count is the cost, not tail width); char4 x float4 dot vs wlT.
    const char (*hl)[272] = hbuf[len & 1];
    if (tid < 16 * OUT_) {
        int m = tid / OUT_, o = tid % OUT_;
        const float4* wp = (const float4*)(wlT + ((size_t)l * OUT_ + o) * H_);
        const char4*  hp = (const char4*)hl[m];
        float s = 0.f;
        #pragma unroll 8
        for (int k4 = 0; k4 < 64; ++k4) {
            char4  hc = hp[k4];
            float4 wv = wp[k4];
            s += (float)hc.x * wv.x + (float)hc.y * wv.y
               + (float)hc.z * wv.z + (float)hc.w * wv.w;
        }
        atomicAdd(&out[(b0 + m) * OUT_ + o], s * QH);
    }
}

extern "C" void kernel_launch(void* const* d_in, const int* in_sizes, int n_in,
                              void* d_out, int out_size, void* d_ws, size_t ws_size,
                              hipStream_t stream) {
    const float* bfeat = (const float*)d_in[0];
    const int*   tidx  = (const int*)d_in[1];
    const int*   tlen  = (const int*)d_in[2];
    const float* W_enc = (const float*)d_in[3];
    const float* b_enc = (const float*)d_in[4];
    const float* W_ih  = (const float*)d_in[5];
    const float* W_hh  = (const float*)d_in[6];
    const float* b_ih  = (const float*)d_in[7];
    const float* b_hh  = (const float*)d_in[8];
    const float* W_lin = (const float*)d_in[9];
    const float* b_lin = (const float*)d_in[10];
    float* out = (float*)d_out;

    char*  whh_i8 = (char*)d_ws;                               // 786,432 B
    float* u = (float*)((char*)d_ws + 786432);                 // 12,288 B
    float* v = (float*)((char*)d_ws + 786432 + 12288);         // 12,288 B
    int* sorted  = (int*)((char*)d_ws + 811008);               // 384 B
    float* wlT   = (float*)((char*)d_ws + 811520);             // 30,720 B (16B aligned)

    prep_all<<<1537, 256, 0, stream>>>(W_enc, b_enc, W_ih, b_ih, b_hh, W_hh, b_lin,
                                       W_lin, tlen, u, v, whh_i8, out, sorted, wlT);
    lstm_main<<<UNITS, 512, 0, stream>>>(bfeat, tidx, tlen, whh_i8, u, v, wlT,
                                         sorted, out);
}

// Round 10
// 148.013 us; speedup vs baseline: 2.1623x; 2.1623x over previous
//
#include <hip/hip_runtime.h>
#include <hip/hip_bf16.h>
#include <stdint.h>

#define B_   64
#define N_   128
#define H_   256
#define FH   1024   // 4*H
#define NT   32     // trunks
#define TL   32     // trunk len
#define LV   3
#define OUT_ 10
#define NTRK 96     // level x trunk instances
#define UNITS 384   // NTRK x 4 batch-quarters (M=16 each)

typedef __attribute__((ext_vector_type(4))) int   int4v;
typedef __attribute__((ext_vector_type(4))) float f32x4;

#define QW  (0.0625f / 127.0f)         // weight quant scale
#define QH  (1.0f / 127.0f)            // h quant scale
#define QS  (QW * QH)                  // combined dequant for i32 acc
#define L2E 1.442695041f               // log2(e)
#define QSI (-L2E * QS)                // sigmoid-gate dequant (pre-negated+scaled)
#define QSG (2.0f * L2E * QS)          // tanh-gate dequant
#define C2  (2.0f * L2E)               // tanh(c) input scale
#define XCLAMP 30.0f                   // exp2 arg clamp: saturation-exact, blocks f32 overflow

__device__ inline float exp2f_(float x) { return __builtin_amdgcn_exp2f(x); }
__device__ inline float rcpf_(float x)  { return __builtin_amdgcn_rcpf(x); }

// merged prep. blocks 0..767: u/v. blocks 768..1535: W_hh->int8 + out init.
// block 1536: LPT sort + W_lin transpose (wlT[l][o][k]).
// (R2 lesson: fusing prep into the main kernel cost 2x on the main dispatch;
// the ~72us total-vs-dispatch gap is fixed harness tax.)
__global__ void prep_all(const float* __restrict__ W_enc, const float* __restrict__ b_enc,
                         const float* __restrict__ W_ih, const float* __restrict__ b_ih,
                         const float* __restrict__ b_hh, const float* __restrict__ W_hh,
                         const float* __restrict__ b_lin, const float* __restrict__ W_lin,
                         const int* __restrict__ trunk_len,
                         float* __restrict__ u, float* __restrict__ v,
                         char* __restrict__ whh_i8, float* __restrict__ out,
                         int* __restrict__ sorted, int* __restrict__ counter,
                         float* __restrict__ wlT) {
    int blk = blockIdx.x;
    int tid = threadIdx.x;
    if (blk < 768) {
        int j = blk * 4 + (tid >> 6);   // 0..3071
        int lane = tid & 63;
        const float4 w  = ((const float4*)(W_ih + (size_t)j * H_))[lane];
        const float4 we = ((const float4*)W_enc)[lane];
        const float4 be = ((const float4*)b_enc)[lane];
        float du = w.x * we.x + w.y * we.y + w.z * we.z + w.w * we.w;
        float dv = w.x * be.x + w.y * be.y + w.z * be.z + w.w * be.w;
        for (int m = 32; m >= 1; m >>= 1) { du += __shfl_xor(du, m); dv += __shfl_xor(dv, m); }
        if (lane == 0) {
            int g = (j & 1023) >> 8;
            float s = (g == 2) ? (2.0f * L2E) : (-L2E);
            u[j] = s * du;
            v[j] = s * (dv + b_ih[j] + b_hh[j]);
        }
    } else if (blk < 1536) {
        int gid = (blk - 768) * 256 + tid;   // 0..196607, each converts 4
        const float4 w = ((const float4*)W_hh)[gid];
        char4 o;
        int a0 = __float2int_rn(w.x * (127.0f / 0.0625f));
        int a1 = __float2int_rn(w.y * (127.0f / 0.0625f));
        int a2 = __float2int_rn(w.z * (127.0f / 0.0625f));
        int a3 = __float2int_rn(w.w * (127.0f / 0.0625f));
        a0 = a0 > 127 ? 127 : (a0 < -127 ? -127 : a0);
        a1 = a1 > 127 ? 127 : (a1 < -127 ? -127 : a1);
        a2 = a2 > 127 ? 127 : (a2 < -127 ? -127 : a2);
        a3 = a3 > 127 ? 127 : (a3 < -127 ? -127 : a3);
        o.x = (char)a0; o.y = (char)a1; o.z = (char)a2; o.w = (char)a3;
        ((char4*)whh_i8)[gid] = o;
        if (gid < B_ * OUT_) {
            int oo = gid % OUT_;
            out[gid] = b_lin[oo] + b_lin[OUT_ + oo] + b_lin[2 * OUT_ + oo];
        }
    } else {
        // LPT order: sorted[rank] = trunk id, rank 0 = longest
        if (tid < NTRK) {
            int li = trunk_len[tid]; if (li < 1) li = 1;
            int rank = 0;
            for (int j2 = 0; j2 < NTRK; ++j2) {
                int lj = trunk_len[j2]; if (lj < 1) lj = 1;
                rank += (lj > li) || (lj == li && j2 < tid);
            }
            sorted[rank] = tid;
        }
        if (tid == 0) *counter = 0;
        // W_lin transpose: wlT[(l*OUT_+o)*H_ + k] = W_lin[(l*H_+k)*OUT_ + o]
        for (int idx = tid; idx < LV * OUT_ * H_; idx += 256) {
            int l = idx / (OUT_ * H_);
            int rem = idx - l * OUT_ * H_;
            int o = rem >> 8;            // / H_
            int k = rem & 255;           // % H_
            wlT[idx] = W_lin[((size_t)l * H_ + k) * OUT_ + o];
        }
    }
}

// Persistent work-queue LSTM (R7 structure — proven 69.7us, pole-bound:
// dispatch = 32 pole steps x 2.18us exactly).
// R9 lesson: co-residency (2 blocks/CU) is PHYSICALLY closed — per-wave
// state ~256 regs x 8 waves = the whole 2048-reg CU file; forcing 4 wv/EU
// spilled 314MB of scratch (FETCH 3.5->314MB, 3.5x regression).
// R10: per-step issue diet. Gate math trans 8->7 per cell: fold sf's rcp
// into the ig rcp — cn = [c*P + (eg-1)(1+ef)] * rcp(P*(1+ef)), with
// P=(1+ei)(1+eg). fminf(x,30) clamps on all exp2 args make the triple
// product overflow-free (and close the pre-existing exp2(C2*cn) NaN
// window): saturation-exact since sigmoid/tanh are flat long before 30.
__global__ __launch_bounds__(512, 2) __attribute__((amdgpu_waves_per_eu(2, 2)))
void lstm_main(const float* __restrict__ bfeat, const int* __restrict__ trunk_idx,
               const int* __restrict__ trunk_len,
               const char* __restrict__ whh_i8,
               const float* __restrict__ u, const float* __restrict__ v,
               const float* __restrict__ wlT, const int* __restrict__ sorted,
               int* __restrict__ counter, float* __restrict__ out) {
    __shared__ __align__(16) char hbuf[2][16][272];   // int8 h, parity dbuf, 256+16 pad
    __shared__ __align__(16) float strunk[TL][16];    // all step scalars for the unit
    __shared__ int sh_uid;

    const int tid = threadIdx.x;
    const int w = tid >> 6;              // wave 0..7 -> col tiles 2w, 2w+1 per gate
    const int lane = tid & 63;
    const int col = lane & 15;
    const int q = lane >> 4;

    // loop-invariant zero C for MFMA chain heads
    int4v z4; z4[0] = 0; z4[1] = 0; z4[2] = 0; z4[3] = 0;
    asm volatile("" : "+v"(z4));

    for (;;) {
        if (tid == 0) sh_uid = atomicAdd(counter, 1);
        __syncthreads();                 // claim visible; orders prev epilogue reads too
        const int uid = sh_uid;
        if (uid >= UNITS) break;

        const int r = uid >> 2, qq = uid & 3;
        const int tt = sorted[r];
        const int l = tt >> 5;
        const int b0 = qq * 16;

        int len = trunk_len[tt];
        if (len < 1) len = 1;
        const int* tix = trunk_idx + tt * TL;
        const char* whh_l = whh_i8 + (size_t)l * FH * H_;

        // scalar preload: thread tid -> (step p = tid>>4, row m = tid&15).
        if (tid < (len << 4))
            strunk[tid >> 4][tid & 15] = bfeat[(b0 + (tid & 15)) * N_ + tix[tid >> 4]];

        // W_hh fragments: wave w owns gate cols j = g*256 + (2w+t)*16 + col.
        int4v Breg[4][2][4];
        #pragma unroll
        for (int g = 0; g < 4; ++g)
            #pragma unroll
            for (int t = 0; t < 2; ++t) {
                int j = g * 256 + (2 * w + t) * 16 + col;
                const char* bp = whh_l + (size_t)j * H_ + q * 16;
                #pragma unroll
                for (int k = 0; k < 4; ++k)
                    Breg[g][t][k] = *(const int4v*)(bp + k * 64);
            }

        float u_r[4][2], v_r[4][2];
        {
            const float* u_l = u + l * FH;
            const float* v_l = v + l * FH;
            #pragma unroll
            for (int g = 0; g < 4; ++g)
                #pragma unroll
                for (int t = 0; t < 2; ++t) {
                    int j = g * 256 + (2 * w + t) * 16 + col;
                    u_r[g][t] = u_l[j];
                    v_r[g][t] = v_l[j];
                }
        }

        // pin Breg: non-rematerializable -> resident or visibly spilled
        #pragma unroll
        for (int g = 0; g < 4; ++g)
            #pragma unroll
            for (int t = 0; t < 2; ++t)
                #pragma unroll
                for (int k = 0; k < 4; ++k)
                    asm volatile("" : "+v"(Breg[g][t][k]));

        float c_r[4][2];                 // [rg][tile]

        __syncthreads();                 // strunk ready

        // ---- peeled step 0: c0 = 0 ----
        {
            f32x4 sv = *(const f32x4*)&strunk[0][q * 4];
            #pragma unroll
            for (int t = 0; t < 2; ++t)
                #pragma unroll
                for (int rg = 0; rg < 4; ++rg) {
                    float xi = fminf(fmaf(sv[rg], u_r[0][t], v_r[0][t]), XCLAMP);
                    float xg = fminf(fmaf(sv[rg], u_r[2][t], v_r[2][t]), XCLAMP);
                    float xo = fminf(fmaf(sv[rg], u_r[3][t], v_r[3][t]), XCLAMP);
                    float ei = exp2f_(xi);
                    float eg = exp2f_(xg);
                    float eo = exp2f_(xo);
                    float cn = (eg - 1.0f) * rcpf_((1.0f + ei) * (1.0f + eg));
                    c_r[rg][t] = cn;
                    float ec = exp2f_(fminf(C2 * cn, XCLAMP));
                    float hq = 127.0f * (ec - 1.0f) * rcpf_((1.0f + eo) * (1.0f + ec));
                    hbuf[1][q * 4 + rg][(2 * w + t) * 16 + col] = (char)__float2int_rn(hq);
                }
            __syncthreads();
        }

        for (int p = 1; p < len; ++p) {
            const int ri = p & 1, wi = ri ^ 1;

            f32x4 sv = *(const f32x4*)&strunk[p][q * 4];

            // k-outer MFMA: one a_f quad live at a time; 8 independent
            // acc chains (4 gates x 2 tiles) per wave.
            int4v acc[4][2];
            #pragma unroll
            for (int k = 0; k < 4; ++k) {
                int4v af = *(const int4v*)&hbuf[ri][col][k * 64 + q * 16];
                if (k == 0) {
                    #pragma unroll
                    for (int g = 0; g < 4; ++g)
                        #pragma unroll
                        for (int t = 0; t < 2; ++t)
                            acc[g][t] = __builtin_amdgcn_mfma_i32_16x16x64_i8(af, Breg[g][t][0], z4, 0, 0, 0);
                } else {
                    #pragma unroll
                    for (int g = 0; g < 4; ++g)
                        #pragma unroll
                        for (int t = 0; t < 2; ++t)
                            acc[g][t] = __builtin_amdgcn_mfma_i32_16x16x64_i8(af, Breg[g][t][k], acc[g][t], 0, 0, 0);
                }
            }

            #pragma unroll
            for (int t = 0; t < 2; ++t)
                #pragma unroll
                for (int rg = 0; rg < 4; ++rg) {
                    float xi = fminf(fmaf((float)acc[0][t][rg], QSI, fmaf(sv[rg], u_r[0][t], v_r[0][t])), XCLAMP);
                    float xf = fminf(fmaf((float)acc[1][t][rg], QSI, fmaf(sv[rg], u_r[1][t], v_r[1][t])), XCLAMP);
                    float xg = fminf(fmaf((float)acc[2][t][rg], QSG, fmaf(sv[rg], u_r[2][t], v_r[2][t])), XCLAMP);
                    float xo = fminf(fmaf((float)acc[3][t][rg], QSI, fmaf(sv[rg], u_r[3][t], v_r[3][t])), XCLAMP);
                    float ei = exp2f_(xi);
                    float ef = exp2f_(xf);
                    float eg = exp2f_(xg);
                    float eo = exp2f_(xo);
                    // merged single-rcp cell update:
                    // cn = c*sig(f) + sig(i)*tanh(g)
                    //    = [c*P + (eg-1)*(1+ef)] / (P*(1+ef)),  P=(1+ei)(1+eg)
                    float af1 = 1.0f + ef;
                    float P   = (1.0f + ei) * (1.0f + eg);
                    float rD  = rcpf_(P * af1);
                    float cn  = rD * fmaf(c_r[rg][t], P, (eg - 1.0f) * af1);
                    c_r[rg][t] = cn;
                    float ec = exp2f_(fminf(C2 * cn, XCLAMP));
                    float hq = 127.0f * (ec - 1.0f) * rcpf_((1.0f + eo) * (1.0f + ec));
                    hbuf[wi][q * 4 + rg][(2 * w + t) * 16 + col] = (char)__float2int_rn(hq);
                }

            __syncthreads();   // lgkmcnt+s_barrier only: no vmem in the loop
        }

        // epilogue: h_last in hbuf[len & 1]; bias pre-initialized by prep.
        // 160 threads, ONE atomicAdd per output element (R4 lesson: atomic
        // count is the cost, not tail width); char4 x float4 dot vs wlT.
        const char (*hl)[272] = hbuf[len & 1];
        if (tid < 16 * OUT_) {
            int m = tid / OUT_, o = tid % OUT_;
            const float4* wp = (const float4*)(wlT + ((size_t)l * OUT_ + o) * H_);
            const char4*  hp = (const char4*)hl[m];
            float s = 0.f;
            #pragma unroll 8
            for (int k4 = 0; k4 < 64; ++k4) {
                char4  hc = hp[k4];
                float4 wv = wp[k4];
                s += (float)hc.x * wv.x + (float)hc.y * wv.y
                   + (float)hc.z * wv.z + (float)hc.w * wv.w;
            }
            atomicAdd(&out[(b0 + m) * OUT_ + o], s * QH);
        }
        // next iteration's claim barrier orders the hbuf reads before reuse
    }
}

extern "C" void kernel_launch(void* const* d_in, const int* in_sizes, int n_in,
                              void* d_out, int out_size, void* d_ws, size_t ws_size,
                              hipStream_t stream) {
    const float* bfeat = (const float*)d_in[0];
    const int*   tidx  = (const int*)d_in[1];
    const int*   tlen  = (const int*)d_in[2];
    const float* W_enc = (const float*)d_in[3];
    const float* b_enc = (const float*)d_in[4];
    const float* W_ih  = (const float*)d_in[5];
    const float* W_hh  = (const float*)d_in[6];
    const float* b_ih  = (const float*)d_in[7];
    const float* b_hh  = (const float*)d_in[8];
    const float* W_lin = (const float*)d_in[9];
    const float* b_lin = (const float*)d_in[10];
    float* out = (float*)d_out;

    char*  whh_i8 = (char*)d_ws;                               // 786,432 B
    float* u = (float*)((char*)d_ws + 786432);                 // 12,288 B
    float* v = (float*)((char*)d_ws + 786432 + 12288);         // 12,288 B
    int* sorted  = (int*)((char*)d_ws + 811008);               // 384 B
    int* counter = (int*)((char*)d_ws + 811392);               // 4 B
    float* wlT   = (float*)((char*)d_ws + 811520);             // 30,720 B (16B aligned)

    prep_all<<<1537, 256, 0, stream>>>(W_enc, b_enc, W_ih, b_ih, b_hh, W_hh, b_lin,
                                       W_lin, tlen, u, v, whh_i8, out, sorted,
                                       counter, wlT);
    lstm_main<<<256, 512, 0, stream>>>(bfeat, tidx, tlen, whh_i8, u, v, wlT,
                                       sorted, counter, out);
}

// Round 12
// 143.882 us; speedup vs baseline: 2.2244x; 1.0287x over previous
//
#include <hip/hip_runtime.h>
#include <hip/hip_bf16.h>
#include <stdint.h>

#define B_   64
#define N_   128
#define H_   256
#define FH   1024   // 4*H
#define NT   32     // trunks
#define TL   32     // trunk len
#define LV   3
#define OUT_ 10
#define NTRK 96     // level x trunk instances
#define UNITS 384   // NTRK x 4 batch-quarters (M=16 each)

typedef __attribute__((ext_vector_type(4))) int   int4v;
typedef __attribute__((ext_vector_type(4))) float f32x4;

#define QW  (0.0625f / 127.0f)         // weight quant scale
#define QH  (1.0f / 127.0f)            // h quant scale
#define QS  (QW * QH)                  // combined dequant for i32 acc
#define L2E 1.442695041f               // log2(e)
#define QSI (-L2E * QS)                // sigmoid-gate dequant (pre-negated+scaled)
#define QSG (2.0f * L2E * QS)          // tanh-gate dequant
#define C2  (2.0f * L2E)               // tanh(c) input scale

__device__ inline float exp2f_(float x) { return __builtin_amdgcn_exp2f(x); }
__device__ inline float rcpf_(float x)  { return __builtin_amdgcn_rcpf(x); }

// merged prep. blocks 0..767: u/v. blocks 768..1535: W_hh->int8 + out init.
// block 1536: LPT sort + counter reset + W_lin transpose (wlT[l][o][k]).
// (R2 lesson: fusing prep into the persistent kernel cost 2x on the main
// dispatch; the ~72us total-vs-dispatch gap is fixed harness tax.)
__global__ void prep_all(const float* __restrict__ W_enc, const float* __restrict__ b_enc,
                         const float* __restrict__ W_ih, const float* __restrict__ b_ih,
                         const float* __restrict__ b_hh, const float* __restrict__ W_hh,
                         const float* __restrict__ b_lin, const float* __restrict__ W_lin,
                         const int* __restrict__ trunk_len,
                         float* __restrict__ u, float* __restrict__ v,
                         char* __restrict__ whh_i8, float* __restrict__ out,
                         int* __restrict__ sorted, int* __restrict__ counter,
                         float* __restrict__ wlT) {
    int blk = blockIdx.x;
    int tid = threadIdx.x;
    if (blk < 768) {
        int j = blk * 4 + (tid >> 6);   // 0..3071
        int lane = tid & 63;
        const float4 w  = ((const float4*)(W_ih + (size_t)j * H_))[lane];
        const float4 we = ((const float4*)W_enc)[lane];
        const float4 be = ((const float4*)b_enc)[lane];
        float du = w.x * we.x + w.y * we.y + w.z * we.z + w.w * we.w;
        float dv = w.x * be.x + w.y * be.y + w.z * be.z + w.w * be.w;
        for (int m = 32; m >= 1; m >>= 1) { du += __shfl_xor(du, m); dv += __shfl_xor(dv, m); }
        if (lane == 0) {
            int g = (j & 1023) >> 8;
            float s = (g == 2) ? (2.0f * L2E) : (-L2E);
            u[j] = s * du;
            v[j] = s * (dv + b_ih[j] + b_hh[j]);
        }
    } else if (blk < 1536) {
        int gid = (blk - 768) * 256 + tid;   // 0..196607, each converts 4
        const float4 w = ((const float4*)W_hh)[gid];
        char4 o;
        int a0 = __float2int_rn(w.x * (127.0f / 0.0625f));
        int a1 = __float2int_rn(w.y * (127.0f / 0.0625f));
        int a2 = __float2int_rn(w.z * (127.0f / 0.0625f));
        int a3 = __float2int_rn(w.w * (127.0f / 0.0625f));
        a0 = a0 > 127 ? 127 : (a0 < -127 ? -127 : a0);
        a1 = a1 > 127 ? 127 : (a1 < -127 ? -127 : a1);
        a2 = a2 > 127 ? 127 : (a2 < -127 ? -127 : a2);
        a3 = a3 > 127 ? 127 : (a3 < -127 ? -127 : a3);
        o.x = (char)a0; o.y = (char)a1; o.z = (char)a2; o.w = (char)a3;
        ((char4*)whh_i8)[gid] = o;
        if (gid < B_ * OUT_) {
            int oo = gid % OUT_;
            out[gid] = b_lin[oo] + b_lin[OUT_ + oo] + b_lin[2 * OUT_ + oo];
        }
    } else {
        // LPT order: sorted[rank] = trunk id, rank 0 = longest
        if (tid < NTRK) {
            int li = trunk_len[tid]; if (li < 1) li = 1;
            int rank = 0;
            for (int j2 = 0; j2 < NTRK; ++j2) {
                int lj = trunk_len[j2]; if (lj < 1) lj = 1;
                rank += (lj > li) || (lj == li && j2 < tid);
            }
            sorted[rank] = tid;
        }
        if (tid == 0) *counter = 0;
        // W_lin transpose: wlT[(l*OUT_+o)*H_ + k] = W_lin[(l*H_+k)*OUT_ + o]
        for (int idx = tid; idx < LV * OUT_ * H_; idx += 256) {
            int l = idx / (OUT_ * H_);
            int rem = idx - l * OUT_ * H_;
            int o = rem >> 8;            // / H_
            int k = rem & 255;           // % H_
            wlT[idx] = W_lin[((size_t)l * H_ + k) * OUT_ + o];
        }
    }
}

// Persistent work-queue LSTM — FINAL (R7 artifact, best measured: 69.7us
// dispatch / 147.06us total). 512 threads = 8 waves, wave owns 2 col-tiles
// per gate. Zero per-step global memory (strunk preload). Measured-closed
// levers: waves/SIMD 4<->2 iso (R5/R6); co-residency impossible — weights
// fill the CU register file (R3/R9 spills); prep fusion -2x (R2); trans
// diet neutral (R10); atomic epilogue must stay 1-atomic-per-element (R4).
// Dispatch = len_max(32) x T_step exactly — pole-latency-bound; T_step is
// the serial recurrence floor (ds_read -> 4-deep MFMA -> gate chain ->
// ds_write -> barrier) with no hardware pipe near ceiling.
__global__ __launch_bounds__(512, 2) __attribute__((amdgpu_waves_per_eu(2, 2)))
void lstm_main(const float* __restrict__ bfeat, const int* __restrict__ trunk_idx,
               const int* __restrict__ trunk_len,
               const char* __restrict__ whh_i8,
               const float* __restrict__ u, const float* __restrict__ v,
               const float* __restrict__ wlT, const int* __restrict__ sorted,
               int* __restrict__ counter, float* __restrict__ out) {
    __shared__ __align__(16) char hbuf[2][16][272];   // int8 h, parity dbuf, 256+16 pad
    __shared__ __align__(16) float strunk[TL][16];    // all step scalars for the unit
    __shared__ int sh_uid;

    const int tid = threadIdx.x;
    const int w = tid >> 6;              // wave 0..7 -> col tiles 2w, 2w+1 per gate
    const int lane = tid & 63;
    const int col = lane & 15;
    const int q = lane >> 4;

    // loop-invariant zero C for MFMA chain heads
    int4v z4; z4[0] = 0; z4[1] = 0; z4[2] = 0; z4[3] = 0;
    asm volatile("" : "+v"(z4));

    for (;;) {
        if (tid == 0) sh_uid = atomicAdd(counter, 1);
        __syncthreads();                 // claim visible; orders prev epilogue reads too
        const int uid = sh_uid;
        if (uid >= UNITS) break;

        const int r = uid >> 2, qq = uid & 3;
        const int tt = sorted[r];
        const int l = tt >> 5;
        const int b0 = qq * 16;

        int len = trunk_len[tt];
        if (len < 1) len = 1;
        const int* tix = trunk_idx + tt * TL;
        const char* whh_l = whh_i8 + (size_t)l * FH * H_;

        // scalar preload: thread tid -> (step p = tid>>4, row m = tid&15).
        // One global load per thread, overlapped with the Breg/u/v loads.
        if (tid < (len << 4))
            strunk[tid >> 4][tid & 15] = bfeat[(b0 + (tid & 15)) * N_ + tix[tid >> 4]];

        // W_hh fragments: wave w owns gate cols j = g*256 + (2w+t)*16 + col.
        int4v Breg[4][2][4];
        #pragma unroll
        for (int g = 0; g < 4; ++g)
            #pragma unroll
            for (int t = 0; t < 2; ++t) {
                int j = g * 256 + (2 * w + t) * 16 + col;
                const char* bp = whh_l + (size_t)j * H_ + q * 16;
                #pragma unroll
                for (int k = 0; k < 4; ++k)
                    Breg[g][t][k] = *(const int4v*)(bp + k * 64);
            }

        float u_r[4][2], v_r[4][2];
        {
            const float* u_l = u + l * FH;
            const float* v_l = v + l * FH;
            #pragma unroll
            for (int g = 0; g < 4; ++g)
                #pragma unroll
                for (int t = 0; t < 2; ++t) {
                    int j = g * 256 + (2 * w + t) * 16 + col;
                    u_r[g][t] = u_l[j];
                    v_r[g][t] = v_l[j];
                }
        }

        // pin Breg: non-rematerializable -> resident or visibly spilled
        #pragma unroll
        for (int g = 0; g < 4; ++g)
            #pragma unroll
            for (int t = 0; t < 2; ++t)
                #pragma unroll
                for (int k = 0; k < 4; ++k)
                    asm volatile("" : "+v"(Breg[g][t][k]));

        float c_r[4][2];                 // [rg][tile]

        __syncthreads();                 // strunk ready

        // ---- peeled step 0: c0 = 0 ----
        {
            f32x4 sv = *(const f32x4*)&strunk[0][q * 4];
            #pragma unroll
            for (int t = 0; t < 2; ++t)
                #pragma unroll
                for (int rg = 0; rg < 4; ++rg) {
                    float xi = fmaf(sv[rg], u_r[0][t], v_r[0][t]);
                    float xg = fmaf(sv[rg], u_r[2][t], v_r[2][t]);
                    float xo = fmaf(sv[rg], u_r[3][t], v_r[3][t]);
                    float ei = exp2f_(xi);
                    float eg = exp2f_(xg);
                    float eo = exp2f_(xo);
                    float cn = (eg - 1.0f) * rcpf_((1.0f + ei) * (1.0f + eg));
                    c_r[rg][t] = cn;
                    float ec = exp2f_(C2 * cn);
                    float hq = 127.0f * (ec - 1.0f) * rcpf_((1.0f + eo) * (1.0f + ec));
                    hbuf[1][q * 4 + rg][(2 * w + t) * 16 + col] = (char)__float2int_rn(hq);
                }
            __syncthreads();
        }

        for (int p = 1; p < len; ++p) {
            const int ri = p & 1, wi = ri ^ 1;

            f32x4 sv = *(const f32x4*)&strunk[p][q * 4];

            // k-outer MFMA: one a_f quad live at a time; 8 independent
            // acc chains (4 gates x 2 tiles) per wave.
            int4v acc[4][2];
            #pragma unroll
            for (int k = 0; k < 4; ++k) {
                int4v af = *(const int4v*)&hbuf[ri][col][k * 64 + q * 16];
                if (k == 0) {
                    #pragma unroll
                    for (int g = 0; g < 4; ++g)
                        #pragma unroll
                        for (int t = 0; t < 2; ++t)
                            acc[g][t] = __builtin_amdgcn_mfma_i32_16x16x64_i8(af, Breg[g][t][0], z4, 0, 0, 0);
                } else {
                    #pragma unroll
                    for (int g = 0; g < 4; ++g)
                        #pragma unroll
                        for (int t = 0; t < 2; ++t)
                            acc[g][t] = __builtin_amdgcn_mfma_i32_16x16x64_i8(af, Breg[g][t][k], acc[g][t], 0, 0, 0);
                }
            }

            #pragma unroll
            for (int t = 0; t < 2; ++t)
                #pragma unroll
                for (int rg = 0; rg < 4; ++rg) {
                    float xi = fmaf((float)acc[0][t][rg], QSI, fmaf(sv[rg], u_r[0][t], v_r[0][t]));
                    float xf = fmaf((float)acc[1][t][rg], QSI, fmaf(sv[rg], u_r[1][t], v_r[1][t]));
                    float xg = fmaf((float)acc[2][t][rg], QSG, fmaf(sv[rg], u_r[2][t], v_r[2][t]));
                    float xo = fmaf((float)acc[3][t][rg], QSI, fmaf(sv[rg], u_r[3][t], v_r[3][t]));
                    float ei = exp2f_(xi);
                    float ef = exp2f_(xf);
                    float eg = exp2f_(xg);
                    float eo = exp2f_(xo);
                    float sf = rcpf_(1.0f + ef);                               // sigmoid(f)
                    float ig = (eg - 1.0f) * rcpf_((1.0f + ei) * (1.0f + eg)); // sig(i)*tanh(g)
                    float cn = fmaf(sf, c_r[rg][t], ig);
                    c_r[rg][t] = cn;
                    float ec = exp2f_(C2 * cn);
                    float hq = 127.0f * (ec - 1.0f) * rcpf_((1.0f + eo) * (1.0f + ec));
                    hbuf[wi][q * 4 + rg][(2 * w + t) * 16 + col] = (char)__float2int_rn(hq);
                }

            __syncthreads();   // lgkmcnt+s_barrier only: no vmem in the loop
        }

        // epilogue: h_last in hbuf[len & 1]; bias pre-initialized by prep.
        // 160 threads, ONE atomicAdd per output element (R4 lesson: atomic
        // count is the cost, not tail width); char4 x float4 dot vs wlT.
        const char (*hl)[272] = hbuf[len & 1];
        if (tid < 16 * OUT_) {
            int m = tid / OUT_, o = tid % OUT_;
            const float4* wp = (const float4*)(wlT + ((size_t)l * OUT_ + o) * H_);
            const char4*  hp = (const char4*)hl[m];
            float s = 0.f;
            #pragma unroll 8
            for (int k4 = 0; k4 < 64; ++k4) {
                char4  hc = hp[k4];
                float4 wv = wp[k4];
                s += (float)hc.x * wv.x + (float)hc.y * wv.y
                   + (float)hc.z * wv.z + (float)hc.w * wv.w;
            }
            atomicAdd(&out[(b0 + m) * OUT_ + o], s * QH);
        }
        // next iteration's claim barrier orders the hbuf reads before reuse
    }
}

extern "C" void kernel_launch(void* const* d_in, const int* in_sizes, int n_in,
                              void* d_out, int out_size, void* d_ws, size_t ws_size,
                              hipStream_t stream) {
    const float* bfeat = (const float*)d_in[0];
    const int*   tidx  = (const int*)d_in[1];
    const int*   tlen  = (const int*)d_in[2];
    const float* W_enc = (const float*)d_in[3];
    const float* b_enc = (const float*)d_in[4];
    const float* W_ih  = (const float*)d_in[5];
    const float* W_hh  = (const float*)d_in[6];
    const float* b_ih  = (const float*)d_in[7];
    const float* b_hh  = (const float*)d_in[8];
    const float* W_lin = (const float*)d_in[9];
    const float* b_lin = (const float*)d_in[10];
    float* out = (float*)d_out;

    char*  whh_i8 = (char*)d_ws;                               // 786,432 B
    float* u = (float*)((char*)d_ws + 786432);                 // 12,288 B
    float* v = (float*)((char*)d_ws + 786432 + 12288);         // 12,288 B
    int* sorted  = (int*)((char*)d_ws + 811008);               // 384 B
    int* counter = (int*)((char*)d_ws + 811392);               // 4 B
    float* wlT   = (float*)((char*)d_ws + 811520);             // 30,720 B (16B aligned)

    prep_all<<<1537, 256, 0, stream>>>(W_enc, b_enc, W_ih, b_ih, b_hh, W_hh, b_lin,
                                       W_lin, tlen, u, v, whh_i8, out, sorted,
                                       counter, wlT);
    lstm_main<<<256, 512, 0, stream>>>(bfeat, tidx, tlen, whh_i8, u, v, wlT,
                                       sorted, counter, out);
}